// Round 2
// baseline (222.408 us; speedup 1.0000x reference)
//
#include <hip/hip_runtime.h>
#include <stdint.h>

typedef __bf16 bf16x8 __attribute__((ext_vector_type(8)));
typedef float floatx4 __attribute__((ext_vector_type(4)));

#define DI __device__ __forceinline__

DI float bf2f(uint16_t u) {
    union { uint32_t i; float f; } v; v.i = ((uint32_t)u) << 16; return v.f;
}
DI uint16_t f2bf(float f) {
    union { float f; uint32_t i; } v; v.f = f;
    uint32_t u = v.i;
    return (uint16_t)((u + 0x7FFFu + ((u >> 16) & 1u)) >> 16);  // RNE
}

// ---------------------------------------------------------------------------
// Kernel 0: dtype detector. Inputs may be fp32 (reference dtype) or bf16
// (harness-converted). Sample 256 uint32 words of x: fp32 normals have
// exponent bits in [64,192] essentially always; packed bf16 pairs ~50%.
// ---------------------------------------------------------------------------
__global__ __launch_bounds__(64) void detect_kernel(
    const uint32_t* __restrict__ x, int* __restrict__ flag)
{
    int lane = threadIdx.x;
    int cnt = 0;
#pragma unroll
    for (int i = 0; i < 4; i++) {
        uint32_t w = x[lane * 4 + i];
        uint32_t e = (w >> 23) & 0xFF;
        if (e >= 64 && e <= 192) cnt++;
    }
    for (int m = 1; m < 64; m <<= 1) cnt += __shfl_xor(cnt, m);
    if (lane == 0) *flag = (cnt >= 240) ? 1 : 0;   // 1 = fp32 inputs
}

// ---------------------------------------------------------------------------
// Kernel 1: projections.  x[b][c][128][128] -> per block (blk=q*2+b):
//   th [blk][4096][32]  (theta, bf16)   phT [blk][4096][32] (phi)
//   gxT[blk][32][4096]  (g, transposed)
// grid: 8 blk x 16 ntiles x 6 chunks (chunk = proj*2 + o-half)
// ---------------------------------------------------------------------------
__global__ __launch_bounds__(256) void proj_kernel(
    const void* __restrict__ x,
    const void* __restrict__ theta_w, const void* __restrict__ theta_b,
    const void* __restrict__ phi_w,   const void* __restrict__ phi_b,
    const void* __restrict__ g_w,     const void* __restrict__ g_b,
    const int* __restrict__ flag,
    uint16_t* __restrict__ th, uint16_t* __restrict__ phT,
    uint16_t* __restrict__ gxT)
{
    int wgid  = blockIdx.x;
    int chunk = wgid % 6;            // wg-uniform
    int ntile = (wgid / 6) % 16;
    int blk   = wgid / 96;
    int p  = chunk >> 1;
    int o0 = (chunk & 1) * 16;
    int n  = ntile * 256 + threadIdx.x;
    int b = blk & 1, q = blk >> 1, qh = q >> 1, qw = q & 1;
    int i = n >> 6, j = n & 63;
    size_t xoff = (size_t)b * 1048576 + (size_t)(qh * 64 + i) * 128 + qw * 64 + j;

    const void* W  = (p == 0) ? theta_w : (p == 1) ? phi_w : g_w;
    const void* Bv = (p == 0) ? theta_b : (p == 1) ? phi_b : g_b;

    float acc[16];
    if (*flag) {                                   // fp32 inputs
        const float* Wf = (const float*)W;
        const float* Bf = (const float*)Bv;
        const float* xf = (const float*)x + xoff;
#pragma unroll
        for (int k = 0; k < 16; k++) acc[k] = Bf[o0 + k];
        for (int c = 0; c < 64; c++) {
            float xv = xf[(size_t)c * 16384];
#pragma unroll
            for (int k = 0; k < 16; k++)
                acc[k] += Wf[(o0 + k) * 64 + c] * xv;
        }
    } else {                                       // bf16 inputs
        const uint16_t* Wh = (const uint16_t*)W;
        const uint16_t* Bh = (const uint16_t*)Bv;
        const uint16_t* xh = (const uint16_t*)x + xoff;
#pragma unroll
        for (int k = 0; k < 16; k++) acc[k] = bf2f(Bh[o0 + k]);
        for (int c = 0; c < 64; c++) {
            float xv = bf2f(xh[(size_t)c * 16384]);
#pragma unroll
            for (int k = 0; k < 16; k++)
                acc[k] += bf2f(Wh[(o0 + k) * 64 + c]) * xv;
        }
    }

    if (p < 2) {
        uint16_t* dst = (p == 0 ? th : phT) + ((size_t)blk * 4096 + n) * 32 + o0;
#pragma unroll
        for (int k = 0; k < 16; k += 2) {
            uint32_t v = (uint32_t)f2bf(acc[k]) | ((uint32_t)f2bf(acc[k + 1]) << 16);
            *(uint32_t*)(dst + k) = v;
        }
    } else {
        uint16_t* dst = gxT + (size_t)blk * 131072 + n;
#pragma unroll
        for (int k = 0; k < 16; k++) dst[(size_t)(o0 + k) * 4096] = f2bf(acc[k]);
    }
}

// ---------------------------------------------------------------------------
// Kernel 2: fused attention (no-max softmax: |s| < ~10 so exp never overflows).
// WG = 4 waves; wave owns 16 Q-rows; loops 64 key-tiles of 64 cols.
// S = mfma(A=Q, B=K) -> C layout (row=quad*4+r, col=lane&15).
// P -> LDS (row stride 68 bf16), read back as B-operand;
// out[o][qrow] = mfma(A=V^T, B=P~).  Row-sum deferred to the end.
// ---------------------------------------------------------------------------
__global__ __launch_bounds__(256) void flash_kernel(
    const uint16_t* __restrict__ th, const uint16_t* __restrict__ phT,
    const uint16_t* __restrict__ gxT, float* __restrict__ yT)
{
    __shared__ uint16_t pbuf[4][16 * 68];   // wave-private strips
    int blk = blockIdx.x >> 6;
    int rt  = blockIdx.x & 63;
    int tid = threadIdx.x;
    int wid = tid >> 6, lane = tid & 63;
    int quad = lane >> 4, low = lane & 15;
    int n0 = rt * 64 + wid * 16;

    const uint16_t* thB = th  + (size_t)blk * 131072;
    const uint16_t* phB = phT + (size_t)blk * 131072;
    const uint16_t* gxB = gxT + (size_t)blk * 131072;

    bf16x8 qf = *(const bf16x8*)(thB + (n0 + low) * 32 + quad * 8);

    floatx4 zero = {0.f, 0.f, 0.f, 0.f};
    floatx4 oacc0 = zero, oacc1 = zero;
    float psum[4] = {0.f, 0.f, 0.f, 0.f};
    uint16_t* myp = pbuf[wid];

    for (int mt = 0; mt < 64; ++mt) {
        int m0 = mt * 64;
        bf16x8 kf0 = *(const bf16x8*)(phB + (m0 +  0 + low) * 32 + quad * 8);
        bf16x8 kf1 = *(const bf16x8*)(phB + (m0 + 16 + low) * 32 + quad * 8);
        bf16x8 kf2 = *(const bf16x8*)(phB + (m0 + 32 + low) * 32 + quad * 8);
        bf16x8 kf3 = *(const bf16x8*)(phB + (m0 + 48 + low) * 32 + quad * 8);
        bf16x8 vf00 = *(const bf16x8*)(gxB + (size_t)( 0 + low) * 4096 + m0 +  0 + quad * 8);
        bf16x8 vf01 = *(const bf16x8*)(gxB + (size_t)(16 + low) * 4096 + m0 +  0 + quad * 8);
        bf16x8 vf10 = *(const bf16x8*)(gxB + (size_t)( 0 + low) * 4096 + m0 + 32 + quad * 8);
        bf16x8 vf11 = *(const bf16x8*)(gxB + (size_t)(16 + low) * 4096 + m0 + 32 + quad * 8);

        floatx4 sa[4];
        sa[0] = __builtin_amdgcn_mfma_f32_16x16x32_bf16(qf, kf0, zero, 0, 0, 0);
        sa[1] = __builtin_amdgcn_mfma_f32_16x16x32_bf16(qf, kf1, zero, 0, 0, 0);
        sa[2] = __builtin_amdgcn_mfma_f32_16x16x32_bf16(qf, kf2, zero, 0, 0, 0);
        sa[3] = __builtin_amdgcn_mfma_f32_16x16x32_bf16(qf, kf3, zero, 0, 0, 0);

#pragma unroll
        for (int t = 0; t < 4; t++) {
#pragma unroll
            for (int r = 0; r < 4; r++) {
                float pv = __expf(sa[t][r]);
                psum[r] += pv;
                myp[(quad * 4 + r) * 68 + t * 16 + low] = f2bf(pv);
            }
        }
        __asm__ volatile("s_waitcnt lgkmcnt(0)" ::: "memory");

        union { uint32_t u[4]; bf16x8 v; } P0, P1;
        const uint32_t* lp = (const uint32_t*)(myp + low * 68 + quad * 8);
#pragma unroll
        for (int w2 = 0; w2 < 4; w2++) P0.u[w2] = lp[w2];
        const uint32_t* lp1 = (const uint32_t*)(myp + low * 68 + 32 + quad * 8);
#pragma unroll
        for (int w2 = 0; w2 < 4; w2++) P1.u[w2] = lp1[w2];

        oacc0 = __builtin_amdgcn_mfma_f32_16x16x32_bf16(vf00, P0.v, oacc0, 0, 0, 0);
        oacc1 = __builtin_amdgcn_mfma_f32_16x16x32_bf16(vf01, P0.v, oacc1, 0, 0, 0);
        oacc0 = __builtin_amdgcn_mfma_f32_16x16x32_bf16(vf10, P1.v, oacc0, 0, 0, 0);
        oacc1 = __builtin_amdgcn_mfma_f32_16x16x32_bf16(vf11, P1.v, oacc1, 0, 0, 0);
        __asm__ volatile("s_waitcnt lgkmcnt(0)" ::: "memory");  // WAR vs next writes
    }

    // deferred row sums: reduce across the 16 lanes of each quad
#pragma unroll
    for (int r = 0; r < 4; r++) {
        float v = psum[r];
        v += __shfl_xor(v, 1); v += __shfl_xor(v, 2);
        v += __shfl_xor(v, 4); v += __shfl_xor(v, 8);
        psum[r] = v;
    }
    float vsel = (low & 2) ? ((low & 1) ? psum[3] : psum[2])
                           : ((low & 1) ? psum[1] : psum[0]);
    float l = __shfl(vsel, (low >> 2) * 16 + low);
    float rinv = 1.0f / l;

    float* yB = yT + (size_t)blk * 131072;
#pragma unroll
    for (int r = 0; r < 4; r++) {
        yB[(size_t)( 0 + quad * 4 + r) * 4096 + n0 + low] = oacc0[r] * rinv;
        yB[(size_t)(16 + quad * 4 + r) * 4096 + n0 + low] = oacc1[r] * rinv;
    }
}

// ---------------------------------------------------------------------------
// Kernel 3: wy[blk][c][n] = sum_o w_w[c][o] * yT[blk][o][n] + w_b[c]
// ---------------------------------------------------------------------------
__global__ __launch_bounds__(256) void wy_kernel(
    const float* __restrict__ yT, const void* __restrict__ w_w,
    const void* __restrict__ w_b, const int* __restrict__ flag,
    float* __restrict__ wy)
{
    int blk = blockIdx.x >> 4, nt = blockIdx.x & 15;
    int n = nt * 256 + threadIdx.x;
    const float* yB = yT + (size_t)blk * 131072 + n;
    float yv[32];
#pragma unroll
    for (int o = 0; o < 32; o++) yv[o] = yB[(size_t)o * 4096];
    float* wB = wy + (size_t)blk * 262144 + n;
    if (*flag) {
        const float* wwf = (const float*)w_w;
        const float* wbf = (const float*)w_b;
        for (int c = 0; c < 64; c++) {
            float acc = wbf[c];
#pragma unroll
            for (int o = 0; o < 32; o++) acc += wwf[c * 32 + o] * yv[o];
            wB[(size_t)c * 4096] = acc;
        }
    } else {
        const uint16_t* wwh = (const uint16_t*)w_w;
        const uint16_t* wbh = (const uint16_t*)w_b;
        for (int c = 0; c < 64; c++) {
            float acc = bf2f(wbh[c]);
#pragma unroll
            for (int o = 0; o < 32; o++) acc += bf2f(wwh[c * 32 + o]) * yv[o];
            wB[(size_t)c * 4096] = acc;
        }
    }
}

// ---------------------------------------------------------------------------
// Kernel 4: BN stats per (q,c) over both batches (8192 values) ->
//   stats[q*64+c] = (scale, shift)
// ---------------------------------------------------------------------------
__global__ __launch_bounds__(256) void stats_kernel(
    const float* __restrict__ wy, const void* __restrict__ gamma,
    const void* __restrict__ beta, const int* __restrict__ flag,
    float2* __restrict__ stats)
{
    int q = blockIdx.x >> 6, c = blockIdx.x & 63;
    int tid = threadIdx.x;
    const float* r0 = wy + ((size_t)(q * 2 + 0) * 64 + c) * 4096;
    const float* r1 = wy + ((size_t)(q * 2 + 1) * 64 + c) * 4096;
    float s = 0.f, ss = 0.f;
    for (int t = tid; t < 4096; t += 256) {
        float a = r0[t], b = r1[t];
        s += a + b; ss += a * a + b * b;
    }
    for (int m = 1; m < 64; m <<= 1) { s += __shfl_xor(s, m); ss += __shfl_xor(ss, m); }
    __shared__ float sh[8];
    int wid = tid >> 6;
    if ((tid & 63) == 0) { sh[wid] = s; sh[4 + wid] = ss; }
    __syncthreads();
    if (tid == 0) {
        float S  = sh[0] + sh[1] + sh[2] + sh[3];
        float SS = sh[4] + sh[5] + sh[6] + sh[7];
        float mu = S * (1.0f / 8192.0f);
        float var = SS * (1.0f / 8192.0f) - mu * mu;
        float gv, bv;
        if (*flag) { gv = ((const float*)gamma)[c]; bv = ((const float*)beta)[c]; }
        else       { gv = bf2f(((const uint16_t*)gamma)[c]); bv = bf2f(((const uint16_t*)beta)[c]); }
        float scale = gv * rsqrtf(var + 1e-5f);
        float shift = bv - mu * scale;
        stats[q * 64 + c] = make_float2(scale, shift);
    }
}

// ---------------------------------------------------------------------------
// Kernel 5: out = (wy * scale + shift) + x, quadrant reassembly.
// Output dtype follows input dtype (fp32 or bf16).
// ---------------------------------------------------------------------------
__global__ __launch_bounds__(256) void final_kernel(
    const float* __restrict__ wy, const float2* __restrict__ stats,
    const void* __restrict__ x, const int* __restrict__ flag,
    void* __restrict__ out)
{
    size_t idx = (size_t)blockIdx.x * 256 + threadIdx.x;
    int n   = (int)(idx & 4095);
    int c   = (int)((idx >> 12) & 63);
    int blk = (int)(idx >> 18);
    int b = blk & 1, q = blk >> 1, qh = q >> 1, qw = q & 1;
    int i = n >> 6, j = n & 63;
    float2 sc = stats[q * 64 + c];
    float v = wy[idx] * sc.x + sc.y;
    size_t xa = ((size_t)(b * 64 + c) * 128 + (qh * 64 + i)) * 128 + qw * 64 + j;
    if (*flag) {
        ((float*)out)[xa] = v + ((const float*)x)[xa];
    } else {
        ((uint16_t*)out)[xa] = f2bf(v + bf2f(((const uint16_t*)x)[xa]));
    }
}

// ---------------------------------------------------------------------------
extern "C" void kernel_launch(void* const* d_in, const int* in_sizes, int n_in,
                              void* d_out, int out_size, void* d_ws, size_t ws_size,
                              hipStream_t stream)
{
    const void* x       = d_in[0];
    const void* g_w     = d_in[1];
    const void* g_b     = d_in[2];
    const void* theta_w = d_in[3];
    const void* theta_b = d_in[4];
    const void* phi_w   = d_in[5];
    const void* phi_b   = d_in[6];
    const void* w_w     = d_in[7];
    const void* w_b     = d_in[8];
    const void* gamma   = d_in[9];
    const void* beta    = d_in[10];

    char* ws = (char*)d_ws;
    int*      flag  = (int*)(ws);                       // 4 B
    float2*   stats = (float2*)(ws + 1024);             // 2 KB
    uint16_t* th    = (uint16_t*)(ws + (1u  << 20));    // 2 MB
    uint16_t* phT   = (uint16_t*)(ws + (3u  << 20));    // 2 MB
    uint16_t* gxT   = (uint16_t*)(ws + (5u  << 20));    // 2 MB
    float*    yT    = (float*)   (ws + (7u  << 20));    // 4 MB
    float*    wy    = (float*)   (ws + (11u << 20));    // 8 MB  (ends at 19 MB)

    detect_kernel<<<1,    64,  0, stream>>>((const uint32_t*)x, flag);
    proj_kernel  <<<768,  256, 0, stream>>>(x, theta_w, theta_b, phi_w, phi_b,
                                            g_w, g_b, flag, th, phT, gxT);
    flash_kernel <<<512,  256, 0, stream>>>(th, phT, gxT, yT);
    wy_kernel    <<<128,  256, 0, stream>>>(yT, w_w, w_b, flag, wy);
    stats_kernel <<<256,  256, 0, stream>>>(wy, gamma, beta, flag, stats);
    final_kernel <<<8192, 256, 0, stream>>>(wy, stats, x, flag, d_out);
}